// Round 14
// baseline (4986.013 us; speedup 1.0000x reference)
//
#include <hip/hip_runtime.h>
#include <hip/hip_bf16.h>
#include <hip/hip_fp8.h>

typedef float f32x4  __attribute__((ext_vector_type(4)));
typedef float f32x16 __attribute__((ext_vector_type(16)));
typedef int   i32x4  __attribute__((ext_vector_type(4)));
typedef int   i32x8  __attribute__((ext_vector_type(8)));

#define NTOK 4096   // B*T
#define TT   512
#define HH   1024
#define VV   32000

#define BM   128
#define BN   256
#define NKT  16     // K-tiles of 64

#define SC1  0x7F7F7F7F          // e8m0 = 127 (2^0) in every byte
#define INVS 0.000244140625f     // 1/4096 undoes the 64*64 pre-scale

#define GLOBAL_AS(p) ((const __attribute__((address_space(1))) void*)(const void*)(p))
#define LDS_AS(p)    ((__attribute__((address_space(3))) void*)(void*)(p))
#define BAR()   asm volatile("s_barrier" ::: "memory")
#define LGKM0() asm volatile("s_waitcnt lgkmcnt(0)" ::: "memory")
#define VM3()   asm volatile("s_waitcnt vmcnt(3)" ::: "memory")
#define SB0()   __builtin_amdgcn_sched_barrier(0)

// ---------------------------------------------------------------------------
// f32 -> e4m3 (x64 uniform pre-scale), all four tensors, one dispatch.
// ---------------------------------------------------------------------------
__global__ __launch_bounds__(256)
void grpo_cvt_all(const float* __restrict__ X,  const float* __restrict__ W,
                  const float* __restrict__ Xr, const float* __restrict__ Wr,
                  unsigned char* __restrict__ Xq,  unsigned char* __restrict__ Wq,
                  unsigned char* __restrict__ Xrq, unsigned char* __restrict__ Wrq)
{
    const int nX8 = NTOK * HH / 8, nW8 = VV * HH / 8;
    const int b1 = nX8, b2 = nX8 + nW8, b3 = b2 + nX8;
    const int total = 2 * (nX8 + nW8);
    const int stride = gridDim.x * 256;
    for (int i = blockIdx.x * 256 + threadIdx.x; i < total; i += stride) {
        const float* s; unsigned char* d; int j;
        if      (i < b1) { s = X;  d = Xq;  j = i; }
        else if (i < b2) { s = W;  d = Wq;  j = i - b1; }
        else if (i < b3) { s = Xr; d = Xrq; j = i - b2; }
        else             { s = Wr; d = Wrq; j = i - b3; }
        f32x4 v0 = *(const f32x4*)(s + (size_t)j * 8);
        f32x4 v1 = *(const f32x4*)(s + (size_t)j * 8 + 4);
        union { unsigned char b[8]; unsigned long long u; } r;
#pragma unroll
        for (int e = 0; e < 4; ++e) r.b[e]     = __hip_fp8_e4m3(v0[e] * 64.0f).__x;
#pragma unroll
        for (int e = 0; e < 4; ++e) r.b[4 + e] = __hip_fp8_e4m3(v1[e] * 64.0f).__x;
        *(unsigned long long*)(d + (size_t)j * 8) = r.u;
    }
}

// ---------------------------------------------------------------------------
// MX-fp8 GEMM (round-10 structure, the measured best: 572us merged), with
// ONE change: __launch_bounds__(512, 6) -> 3 blocks/CU (LDS 3x48KB=144<=160,
// VGPR cap 85 > the 60 this kernel measured). r11/r12/r13 showed occupancy,
// not schedule, is the binding lever in the fp8 regime.
// Geometry: 128x256 tile, BK=64, mfma_scale 32x32x64 (uniform scales=1.0),
// 8 waves of 64x64. LDS: [buf][A 8KB | B 16KB], 2 bufs = 48KB.
// Phase t: read 8 x b128 (buf t&1); LGKM0+BAR (cross-wave WAR); stage tile
// t+2 into same buf (3 gloads); SB0; 4 MFMA (setprio); vmcnt(3) drains t+1;
// BAR. Prologue stages t0,t1; vmcnt(3) = t0 landed.
// Logits come out x4096; epilogue multiplies by 1/4096 (exact).
// ---------------------------------------------------------------------------
__global__ __launch_bounds__(512, 6)
void grpo_gemm_f8(const unsigned char* __restrict__ Xq,  const unsigned char* __restrict__ Wq,
                  const unsigned char* __restrict__ Xrq, const unsigned char* __restrict__ Wrq,
                  const int* __restrict__ ids,
                  float* __restrict__ S_p, float* __restrict__ SEL_p,
                  float* __restrict__ S_r, float* __restrict__ SEL_r)
{
    __shared__ int ldsw[12288];   // 48 KiB
    const int tid  = threadIdx.x;
    const int lane = tid & 63;
    const int wid  = tid >> 6;
    const int wr   = wid >> 2;        // 0..1 (M split: 2 x 64)
    const int wc   = wid & 3;         // 0..3 (N split: 4 x 64)
    const int l31  = lane & 31;
    const int hi   = lane >> 5;
    const int swz  = (l31 >> 1) & 3;
    const int s0   = ((2 * hi)     ^ swz) * 4;   // int offsets within 64B row
    const int s1   = ((2 * hi + 1) ^ swz) * 4;

    const int zz = blockIdx.z;
    const unsigned char* Xs = zz ? Xrq : Xq;
    const unsigned char* Ws = zz ? Wrq : Wq;
    float* S   = zz ? S_r   : S_p;
    float* SEL = zz ? SEL_r : SEL_p;

    const int m0 = blockIdx.x * BM;
    const int n0 = blockIdx.y * BN;

    // fragment row bases (int offsets; row = 16 ints). mi/ni=1 adds 512.
    const int arow0 = (wr * 64 + l31) * 16;
    const int brow0 = (wc * 64 + l31) * 16;

    // staging: A = 512 chunks (1/thread), B = 1024 chunks (2/thread)
    const int aRow  = tid >> 2;
    const int aSlot = ((tid & 3) ^ ((tid >> 3) & 3)) * 16;   // inverse swizzle, bytes
    const unsigned char* gAb  = Xs + (size_t)(m0 + aRow) * HH + aSlot;
    const unsigned char* gBb0 = Ws + (size_t)(n0 + aRow) * HH + aSlot;
    const unsigned char* gBb1 = Ws + (size_t)(n0 + 128 + aRow) * HH + aSlot;
    char* ldsc = (char*)ldsw;
    char* dA   = ldsc + wid * 1024;            // + buf*24576
    char* dB0  = ldsc + 8192 + wid * 1024;
    char* dB1  = ldsc + 16384 + wid * 1024;

#define STAGE(BOFF, KC)                                                             \
    do {                                                                            \
        __builtin_amdgcn_global_load_lds(GLOBAL_AS(gAb  + (KC)), LDS_AS(dA  + (BOFF)), 16, 0, 0); \
        __builtin_amdgcn_global_load_lds(GLOBAL_AS(gBb0 + (KC)), LDS_AS(dB0 + (BOFF)), 16, 0, 0); \
        __builtin_amdgcn_global_load_lds(GLOBAL_AS(gBb1 + (KC)), LDS_AS(dB1 + (BOFF)), 16, 0, 0); \
    } while (0)

    f32x16 acc[2][2];
#pragma unroll
    for (int mi = 0; mi < 2; ++mi)
#pragma unroll
        for (int ni = 0; ni < 2; ++ni)
            acc[mi][ni] = (f32x16)0.0f;

    // ---- prologue ----
    STAGE(0, 0);
    STAGE(24576, 64);
    VM3();
    BAR();

#define F8_BODY(BOFF, TNEXT)                                                        \
    {                                                                               \
        const int ab = (BOFF) / 4;                                                  \
        const int bb = (BOFF) / 4 + 2048;                                           \
        i32x4 a0l = *(const i32x4*)(ldsw + ab + arow0 + s0);                        \
        i32x4 a0h = *(const i32x4*)(ldsw + ab + arow0 + s1);                        \
        i32x4 a1l = *(const i32x4*)(ldsw + ab + arow0 + 512 + s0);                  \
        i32x4 a1h = *(const i32x4*)(ldsw + ab + arow0 + 512 + s1);                  \
        i32x4 b0l = *(const i32x4*)(ldsw + bb + brow0 + s0);                        \
        i32x4 b0h = *(const i32x4*)(ldsw + bb + brow0 + s1);                        \
        i32x4 b1l = *(const i32x4*)(ldsw + bb + brow0 + 512 + s0);                  \
        i32x4 b1h = *(const i32x4*)(ldsw + bb + brow0 + 512 + s1);                  \
        i32x8 a0 = __builtin_shufflevector(a0l, a0h, 0, 1, 2, 3, 4, 5, 6, 7);       \
        i32x8 a1 = __builtin_shufflevector(a1l, a1h, 0, 1, 2, 3, 4, 5, 6, 7);       \
        i32x8 b0 = __builtin_shufflevector(b0l, b0h, 0, 1, 2, 3, 4, 5, 6, 7);       \
        i32x8 b1 = __builtin_shufflevector(b1l, b1h, 0, 1, 2, 3, 4, 5, 6, 7);       \
        LGKM0(); BAR();                                                             \
        STAGE((((TNEXT) & 1) * 24576), (((TNEXT) & (NKT - 1)) * 64));               \
        SB0();                                                                      \
        __builtin_amdgcn_s_setprio(1);                                              \
        acc[0][0] = __builtin_amdgcn_mfma_scale_f32_32x32x64_f8f6f4(a0, b0, acc[0][0], 0, 0, 0, SC1, 0, SC1); \
        acc[0][1] = __builtin_amdgcn_mfma_scale_f32_32x32x64_f8f6f4(a0, b1, acc[0][1], 0, 0, 0, SC1, 0, SC1); \
        acc[1][0] = __builtin_amdgcn_mfma_scale_f32_32x32x64_f8f6f4(a1, b0, acc[1][0], 0, 0, 0, SC1, 0, SC1); \
        acc[1][1] = __builtin_amdgcn_mfma_scale_f32_32x32x64_f8f6f4(a1, b1, acc[1][1], 0, 0, 0, SC1, 0, SC1); \
        __builtin_amdgcn_s_setprio(0);                                              \
        VM3(); BAR();                                                               \
    }

    // ---- main loop: 16 K-tiles, double-buffered ----
#pragma unroll 1
    for (int t = 0; t < NKT; t += 2) {
        F8_BODY(0,     t + 2);   // read buf0 (tile t),   stage tile t+2 -> buf0
        F8_BODY(24576, t + 3);   // read buf1 (tile t+1), stage tile t+3 -> buf1
    }

    // ---- epilogue: exp-sum per token row + selected logit ----
    // 32x32 C/D: col = lane&31, row = (rg&3) + 8*(rg>>2) + 4*(lane>>5)
#pragma unroll
    for (int mi = 0; mi < 2; ++mi) {
#pragma unroll
        for (int rg = 0; rg < 16; ++rg) {
            const int row = m0 + wr * 64 + mi * 32 + (rg & 3) + 8 * (rg >> 2) + 4 * hi;
            const float v0 = acc[mi][0][rg] * INVS;
            const float v1 = acc[mi][1][rg] * INVS;
            float s = __expf(v0) + __expf(v1);
            s += __shfl_xor(s, 1, 64);
            s += __shfl_xor(s, 2, 64);
            s += __shfl_xor(s, 4, 64);
            s += __shfl_xor(s, 8, 64);
            s += __shfl_xor(s, 16, 64);
            if (l31 == 0) atomicAdd(&S[row], s);

            const int id = ids[row];
            const int c0 = n0 + wc * 64 + l31;
            if (id == c0)      SEL[row] = v0;
            if (id == c0 + 32) SEL[row] = v1;
        }
    }
#undef F8_BODY
#undef STAGE
}

// ---------------------------------------------------------------------------
// Zero S accumulators (8192 floats).
// ---------------------------------------------------------------------------
__global__ void grpo_init(float* __restrict__ p)
{
    p[blockIdx.x * 1024 + threadIdx.x] = 0.f;
}

// ---------------------------------------------------------------------------
// logp in-place over SEL: lp = SEL - log(S).
// ---------------------------------------------------------------------------
__global__ __launch_bounds__(1024)
void grpo_prep(const float* __restrict__ S_p, const float* __restrict__ S_r,
               float* __restrict__ lp_p, float* __restrict__ lp_r)
{
    int i = blockIdx.x * 1024 + threadIdx.x;
    lp_p[i] = lp_p[i] - logf(S_p[i]);
    lp_r[i] = lp_r[i] - logf(S_r[i]);
}

// ---------------------------------------------------------------------------
// Exact rank-819 threshold (k = int(4096*0.2) = 819), parallel over 64 CUs.
// ---------------------------------------------------------------------------
__global__ __launch_bounds__(64)
void grpo_thresh(const float* __restrict__ lp_r, float* __restrict__ thr)
{
    __shared__ float sh[NTOK];
    for (int i = threadIdx.x; i < NTOK; i += 64) sh[i] = lp_r[i];
    __syncthreads();
    const float v = sh[blockIdx.x * 64 + threadIdx.x];
    int lt = 0, eq = 0;
#pragma unroll 4
    for (int j = 0; j < NTOK; ++j) {
        float u = sh[j];
        lt += (u < v);
        eq += (u == v);
    }
    if (lt <= 818 && 818 < lt + eq) thr[0] = v;
}

// ---------------------------------------------------------------------------
// Final reductions -> 3 scalars. coef_1 == 1 exactly -> ppo = -adv, clip = 0.
// ---------------------------------------------------------------------------
__global__ __launch_bounds__(1024)
void grpo_final(const float* __restrict__ lp_p, const float* __restrict__ lp_r,
                const float* __restrict__ thr,
                const float* __restrict__ am, const float* __restrict__ adv,
                float* __restrict__ out)
{
    __shared__ double red[3][16];
    const int tid = threadIdx.x;
    const float t = thr[0];

    double s_loss = 0.0, s_kl = 0.0, s_am = 0.0;
    for (int i = tid; i < NTOK; i += 1024) {
        float a  = am[i];
        float pr = lp_r[i], pp = lp_p[i];
        float lr = pr - pp;
        float k3 = expf(lr) - lr - 1.0f;
        float kl = (pr <= t) ? k3 * 5.0f : 0.0f;
        float ad = adv[i / TT];
        float ptl = -ad + 0.04f * kl;
        s_loss += (double)(ptl * a);
        s_kl   += (double)(kl * a);
        s_am   += (double)a;
    }
#pragma unroll
    for (int off = 32; off; off >>= 1) {
        s_loss += __shfl_down(s_loss, off, 64);
        s_kl   += __shfl_down(s_kl,   off, 64);
        s_am   += __shfl_down(s_am,   off, 64);
    }
    const int wid = tid >> 6;
    if ((tid & 63) == 0) { red[0][wid] = s_loss; red[1][wid] = s_kl; red[2][wid] = s_am; }
    __syncthreads();
    if (tid == 0) {
        double L = 0, K = 0, A = 0;
        for (int w = 0; w < 16; ++w) { L += red[0][w]; K += red[1][w]; A += red[2][w]; }
        double norm = A < 1.0 ? 1.0 : A;
        out[0] = (float)(L / norm);
        out[1] = (float)(K / norm);
        out[2] = 0.0f;
    }
}

extern "C" void kernel_launch(void* const* d_in, const int* in_sizes, int n_in,
                              void* d_out, int out_size, void* d_ws, size_t ws_size,
                              hipStream_t stream)
{
    const float* X   = (const float*)d_in[0];
    const float* W   = (const float*)d_in[1];
    const int*   ids = (const int*)  d_in[2];
    const float* am  = (const float*)d_in[3];
    const float* adv = (const float*)d_in[4];
    const float* Xr  = (const float*)d_in[5];
    const float* Wr  = (const float*)d_in[6];
    float* out = (float*)d_out;

    float* S_p  = (float*)d_ws;
    float* S_r  = S_p + NTOK;
    float* lp_p = S_r + NTOK;      // SEL_p, overwritten in-place by prep
    float* lp_r = lp_p + NTOK;     // SEL_r
    float* thr  = S_p;             // reused after S consumed

    const size_t q_off = 65536;
    const size_t nX = (size_t)NTOK * HH, nW = (size_t)VV * HH;

    unsigned char* Xq  = (unsigned char*)d_ws + q_off;
    unsigned char* Wq  = Xq + nX;
    unsigned char* Xrq = Wq + nW;
    unsigned char* Wrq = Xrq + nX;

    hipLaunchKernelGGL(grpo_init, dim3(8), dim3(1024), 0, stream, S_p);

    hipLaunchKernelGGL(grpo_cvt_all, dim3(4096), dim3(256), 0, stream,
                       X, W, Xr, Wr, Xq, Wq, Xrq, Wrq);

    dim3 grid(NTOK / BM, VV / BN, 2);   // 32 x 125 x 2; m fastest
    hipLaunchKernelGGL(grpo_gemm_f8, grid, dim3(512), 0, stream,
                       Xq, Wq, Xrq, Wrq, ids, S_p, lp_p, S_r, lp_r);

    hipLaunchKernelGGL(grpo_prep,   dim3(4),  dim3(1024), 0, stream, S_p, S_r, lp_p, lp_r);
    hipLaunchKernelGGL(grpo_thresh, dim3(64), dim3(64),   0, stream, lp_r, thr);
    hipLaunchKernelGGL(grpo_final,  dim3(1),  dim3(1024), 0, stream, lp_p, lp_r, thr, am, adv, out);
}

// Round 15
// 688.409 us; speedup vs baseline: 7.2428x; 7.2428x over previous
//
#include <hip/hip_runtime.h>
#include <hip/hip_bf16.h>
#include <hip/hip_fp8.h>

typedef float f32x4  __attribute__((ext_vector_type(4)));
typedef float f32x16 __attribute__((ext_vector_type(16)));
typedef int   i32x4  __attribute__((ext_vector_type(4)));
typedef int   i32x8  __attribute__((ext_vector_type(8)));

#define NTOK 4096   // B*T
#define TT   512
#define HH   1024
#define VV   32000

#define BM   128
#define BN   256
#define NKT  16     // K-tiles of 64

#define SC1  0x7F7F7F7F          // e8m0 = 127 (2^0) in every byte
#define INVS 0.000244140625f     // 1/4096 undoes the 64*64 pre-scale

#define GLOBAL_AS(p) ((const __attribute__((address_space(1))) void*)(const void*)(p))
#define LDS_AS(p)    ((__attribute__((address_space(3))) void*)(void*)(p))
#define BAR()   asm volatile("s_barrier" ::: "memory")
#define LGKM0() asm volatile("s_waitcnt lgkmcnt(0)" ::: "memory")
#define VM3()   asm volatile("s_waitcnt vmcnt(3)" ::: "memory")
#define SB0()   __builtin_amdgcn_sched_barrier(0)

// ---------------------------------------------------------------------------
// f32 -> e4m3 (x64 uniform pre-scale), all four tensors, one dispatch.
// ---------------------------------------------------------------------------
__global__ __launch_bounds__(256)
void grpo_cvt_all(const float* __restrict__ X,  const float* __restrict__ W,
                  const float* __restrict__ Xr, const float* __restrict__ Wr,
                  unsigned char* __restrict__ Xq,  unsigned char* __restrict__ Wq,
                  unsigned char* __restrict__ Xrq, unsigned char* __restrict__ Wrq)
{
    const int nX8 = NTOK * HH / 8, nW8 = VV * HH / 8;
    const int b1 = nX8, b2 = nX8 + nW8, b3 = b2 + nX8;
    const int total = 2 * (nX8 + nW8);
    const int stride = gridDim.x * 256;
    for (int i = blockIdx.x * 256 + threadIdx.x; i < total; i += stride) {
        const float* s; unsigned char* d; int j;
        if      (i < b1) { s = X;  d = Xq;  j = i; }
        else if (i < b2) { s = W;  d = Wq;  j = i - b1; }
        else if (i < b3) { s = Xr; d = Xrq; j = i - b2; }
        else             { s = Wr; d = Wrq; j = i - b3; }
        f32x4 v0 = *(const f32x4*)(s + (size_t)j * 8);
        f32x4 v1 = *(const f32x4*)(s + (size_t)j * 8 + 4);
        union { unsigned char b[8]; unsigned long long u; } r;
#pragma unroll
        for (int e = 0; e < 4; ++e) r.b[e]     = __hip_fp8_e4m3(v0[e] * 64.0f).__x;
#pragma unroll
        for (int e = 0; e < 4; ++e) r.b[4 + e] = __hip_fp8_e4m3(v1[e] * 64.0f).__x;
        *(unsigned long long*)(d + (size_t)j * 8) = r.u;
    }
}

// ---------------------------------------------------------------------------
// MX-fp8 GEMM = round-10 kernel (best measured: 572us merged GEMM, 691 total)
// with ONE change: __launch_bounds__(512) (no min-waves arg). r10's (512,4)
// capped residency at 2 blocks/CU; resources (VGPR 60 <= 85, LDS 3x48=144
// <= 160KB) allow 3 blocks = 24 waves/CU. r14 proved the min-waves arg
// strangles the register allocator (VGPR 40 -> acc spill, 13GB scratch);
// dropping the arg lets the allocator keep acc in regs while the runtime
// grants the 3rd block via LDS headroom.
// Geometry: 128x256 tile, BK=64, mfma_scale 32x32x64 (uniform scales=1.0),
// 8 waves of 64x64. LDS: [buf][A 8KB | B 16KB], 2 bufs = 48KB.
// Phase t: read 8 x b128 (buf t&1); LGKM0+BAR (cross-wave WAR); stage tile
// t+2 into same buf (3 gloads); SB0; 4 MFMA (setprio); vmcnt(3) drains t+1;
// BAR. Prologue stages t0,t1; vmcnt(3) = t0 landed.
// Logits come out x4096; epilogue multiplies by 1/4096 (exact).
// ---------------------------------------------------------------------------
__global__ __launch_bounds__(512)
void grpo_gemm_f8(const unsigned char* __restrict__ Xq,  const unsigned char* __restrict__ Wq,
                  const unsigned char* __restrict__ Xrq, const unsigned char* __restrict__ Wrq,
                  const int* __restrict__ ids,
                  float* __restrict__ S_p, float* __restrict__ SEL_p,
                  float* __restrict__ S_r, float* __restrict__ SEL_r)
{
    __shared__ int ldsw[12288];   // 48 KiB
    const int tid  = threadIdx.x;
    const int lane = tid & 63;
    const int wid  = tid >> 6;
    const int wr   = wid >> 2;        // 0..1 (M split: 2 x 64)
    const int wc   = wid & 3;         // 0..3 (N split: 4 x 64)
    const int l31  = lane & 31;
    const int hi   = lane >> 5;
    const int swz  = (l31 >> 1) & 3;
    const int s0   = ((2 * hi)     ^ swz) * 4;   // int offsets within 64B row
    const int s1   = ((2 * hi + 1) ^ swz) * 4;

    const int zz = blockIdx.z;
    const unsigned char* Xs = zz ? Xrq : Xq;
    const unsigned char* Ws = zz ? Wrq : Wq;
    float* S   = zz ? S_r   : S_p;
    float* SEL = zz ? SEL_r : SEL_p;

    const int m0 = blockIdx.x * BM;
    const int n0 = blockIdx.y * BN;

    // fragment row bases (int offsets; row = 16 ints). mi/ni=1 adds 512.
    const int arow0 = (wr * 64 + l31) * 16;
    const int brow0 = (wc * 64 + l31) * 16;

    // staging: A = 512 chunks (1/thread), B = 1024 chunks (2/thread)
    const int aRow  = tid >> 2;
    const int aSlot = ((tid & 3) ^ ((tid >> 3) & 3)) * 16;   // inverse swizzle, bytes
    const unsigned char* gAb  = Xs + (size_t)(m0 + aRow) * HH + aSlot;
    const unsigned char* gBb0 = Ws + (size_t)(n0 + aRow) * HH + aSlot;
    const unsigned char* gBb1 = Ws + (size_t)(n0 + 128 + aRow) * HH + aSlot;
    char* ldsc = (char*)ldsw;
    char* dA   = ldsc + wid * 1024;            // + buf*24576
    char* dB0  = ldsc + 8192 + wid * 1024;
    char* dB1  = ldsc + 16384 + wid * 1024;

#define STAGE(BOFF, KC)                                                             \
    do {                                                                            \
        __builtin_amdgcn_global_load_lds(GLOBAL_AS(gAb  + (KC)), LDS_AS(dA  + (BOFF)), 16, 0, 0); \
        __builtin_amdgcn_global_load_lds(GLOBAL_AS(gBb0 + (KC)), LDS_AS(dB0 + (BOFF)), 16, 0, 0); \
        __builtin_amdgcn_global_load_lds(GLOBAL_AS(gBb1 + (KC)), LDS_AS(dB1 + (BOFF)), 16, 0, 0); \
    } while (0)

    f32x16 acc[2][2];
#pragma unroll
    for (int mi = 0; mi < 2; ++mi)
#pragma unroll
        for (int ni = 0; ni < 2; ++ni)
            acc[mi][ni] = (f32x16)0.0f;

    // ---- prologue ----
    STAGE(0, 0);
    STAGE(24576, 64);
    VM3();
    BAR();

#define F8_BODY(BOFF, TNEXT)                                                        \
    {                                                                               \
        const int ab = (BOFF) / 4;                                                  \
        const int bb = (BOFF) / 4 + 2048;                                           \
        i32x4 a0l = *(const i32x4*)(ldsw + ab + arow0 + s0);                        \
        i32x4 a0h = *(const i32x4*)(ldsw + ab + arow0 + s1);                        \
        i32x4 a1l = *(const i32x4*)(ldsw + ab + arow0 + 512 + s0);                  \
        i32x4 a1h = *(const i32x4*)(ldsw + ab + arow0 + 512 + s1);                  \
        i32x4 b0l = *(const i32x4*)(ldsw + bb + brow0 + s0);                        \
        i32x4 b0h = *(const i32x4*)(ldsw + bb + brow0 + s1);                        \
        i32x4 b1l = *(const i32x4*)(ldsw + bb + brow0 + 512 + s0);                  \
        i32x4 b1h = *(const i32x4*)(ldsw + bb + brow0 + 512 + s1);                  \
        i32x8 a0 = __builtin_shufflevector(a0l, a0h, 0, 1, 2, 3, 4, 5, 6, 7);       \
        i32x8 a1 = __builtin_shufflevector(a1l, a1h, 0, 1, 2, 3, 4, 5, 6, 7);       \
        i32x8 b0 = __builtin_shufflevector(b0l, b0h, 0, 1, 2, 3, 4, 5, 6, 7);       \
        i32x8 b1 = __builtin_shufflevector(b1l, b1h, 0, 1, 2, 3, 4, 5, 6, 7);       \
        LGKM0(); BAR();                                                             \
        STAGE((((TNEXT) & 1) * 24576), (((TNEXT) & (NKT - 1)) * 64));               \
        SB0();                                                                      \
        __builtin_amdgcn_s_setprio(1);                                              \
        acc[0][0] = __builtin_amdgcn_mfma_scale_f32_32x32x64_f8f6f4(a0, b0, acc[0][0], 0, 0, 0, SC1, 0, SC1); \
        acc[0][1] = __builtin_amdgcn_mfma_scale_f32_32x32x64_f8f6f4(a0, b1, acc[0][1], 0, 0, 0, SC1, 0, SC1); \
        acc[1][0] = __builtin_amdgcn_mfma_scale_f32_32x32x64_f8f6f4(a1, b0, acc[1][0], 0, 0, 0, SC1, 0, SC1); \
        acc[1][1] = __builtin_amdgcn_mfma_scale_f32_32x32x64_f8f6f4(a1, b1, acc[1][1], 0, 0, 0, SC1, 0, SC1); \
        __builtin_amdgcn_s_setprio(0);                                              \
        VM3(); BAR();                                                               \
    }

    // ---- main loop: 16 K-tiles, double-buffered ----
#pragma unroll 1
    for (int t = 0; t < NKT; t += 2) {
        F8_BODY(0,     t + 2);   // read buf0 (tile t),   stage tile t+2 -> buf0
        F8_BODY(24576, t + 3);   // read buf1 (tile t+1), stage tile t+3 -> buf1
    }

    // ---- epilogue: exp-sum per token row + selected logit ----
    // 32x32 C/D: col = lane&31, row = (rg&3) + 8*(rg>>2) + 4*(lane>>5)
#pragma unroll
    for (int mi = 0; mi < 2; ++mi) {
#pragma unroll
        for (int rg = 0; rg < 16; ++rg) {
            const int row = m0 + wr * 64 + mi * 32 + (rg & 3) + 8 * (rg >> 2) + 4 * hi;
            const float v0 = acc[mi][0][rg] * INVS;
            const float v1 = acc[mi][1][rg] * INVS;
            float s = __expf(v0) + __expf(v1);
            s += __shfl_xor(s, 1, 64);
            s += __shfl_xor(s, 2, 64);
            s += __shfl_xor(s, 4, 64);
            s += __shfl_xor(s, 8, 64);
            s += __shfl_xor(s, 16, 64);
            if (l31 == 0) atomicAdd(&S[row], s);

            const int id = ids[row];
            const int c0 = n0 + wc * 64 + l31;
            if (id == c0)      SEL[row] = v0;
            if (id == c0 + 32) SEL[row] = v1;
        }
    }
#undef F8_BODY
#undef STAGE
}

// ---------------------------------------------------------------------------
// Zero S accumulators (8192 floats).
// ---------------------------------------------------------------------------
__global__ void grpo_init(float* __restrict__ p)
{
    p[blockIdx.x * 1024 + threadIdx.x] = 0.f;
}

// ---------------------------------------------------------------------------
// logp in-place over SEL: lp = SEL - log(S).
// ---------------------------------------------------------------------------
__global__ __launch_bounds__(1024)
void grpo_prep(const float* __restrict__ S_p, const float* __restrict__ S_r,
               float* __restrict__ lp_p, float* __restrict__ lp_r)
{
    int i = blockIdx.x * 1024 + threadIdx.x;
    lp_p[i] = lp_p[i] - logf(S_p[i]);
    lp_r[i] = lp_r[i] - logf(S_r[i]);
}

// ---------------------------------------------------------------------------
// Exact rank-819 threshold (k = int(4096*0.2) = 819), parallel over 64 CUs.
// ---------------------------------------------------------------------------
__global__ __launch_bounds__(64)
void grpo_thresh(const float* __restrict__ lp_r, float* __restrict__ thr)
{
    __shared__ float sh[NTOK];
    for (int i = threadIdx.x; i < NTOK; i += 64) sh[i] = lp_r[i];
    __syncthreads();
    const float v = sh[blockIdx.x * 64 + threadIdx.x];
    int lt = 0, eq = 0;
#pragma unroll 4
    for (int j = 0; j < NTOK; ++j) {
        float u = sh[j];
        lt += (u < v);
        eq += (u == v);
    }
    if (lt <= 818 && 818 < lt + eq) thr[0] = v;
}

// ---------------------------------------------------------------------------
// Final reductions -> 3 scalars. coef_1 == 1 exactly -> ppo = -adv, clip = 0.
// ---------------------------------------------------------------------------
__global__ __launch_bounds__(1024)
void grpo_final(const float* __restrict__ lp_p, const float* __restrict__ lp_r,
                const float* __restrict__ thr,
                const float* __restrict__ am, const float* __restrict__ adv,
                float* __restrict__ out)
{
    __shared__ double red[3][16];
    const int tid = threadIdx.x;
    const float t = thr[0];

    double s_loss = 0.0, s_kl = 0.0, s_am = 0.0;
    for (int i = tid; i < NTOK; i += 1024) {
        float a  = am[i];
        float pr = lp_r[i], pp = lp_p[i];
        float lr = pr - pp;
        float k3 = expf(lr) - lr - 1.0f;
        float kl = (pr <= t) ? k3 * 5.0f : 0.0f;
        float ad = adv[i / TT];
        float ptl = -ad + 0.04f * kl;
        s_loss += (double)(ptl * a);
        s_kl   += (double)(kl * a);
        s_am   += (double)a;
    }
#pragma unroll
    for (int off = 32; off; off >>= 1) {
        s_loss += __shfl_down(s_loss, off, 64);
        s_kl   += __shfl_down(s_kl,   off, 64);
        s_am   += __shfl_down(s_am,   off, 64);
    }
    const int wid = tid >> 6;
    if ((tid & 63) == 0) { red[0][wid] = s_loss; red[1][wid] = s_kl; red[2][wid] = s_am; }
    __syncthreads();
    if (tid == 0) {
        double L = 0, K = 0, A = 0;
        for (int w = 0; w < 16; ++w) { L += red[0][w]; K += red[1][w]; A += red[2][w]; }
        double norm = A < 1.0 ? 1.0 : A;
        out[0] = (float)(L / norm);
        out[1] = (float)(K / norm);
        out[2] = 0.0f;
    }
}

extern "C" void kernel_launch(void* const* d_in, const int* in_sizes, int n_in,
                              void* d_out, int out_size, void* d_ws, size_t ws_size,
                              hipStream_t stream)
{
    const float* X   = (const float*)d_in[0];
    const float* W   = (const float*)d_in[1];
    const int*   ids = (const int*)  d_in[2];
    const float* am  = (const float*)d_in[3];
    const float* adv = (const float*)d_in[4];
    const float* Xr  = (const float*)d_in[5];
    const float* Wr  = (const float*)d_in[6];
    float* out = (float*)d_out;

    float* S_p  = (float*)d_ws;
    float* S_r  = S_p + NTOK;
    float* lp_p = S_r + NTOK;      // SEL_p, overwritten in-place by prep
    float* lp_r = lp_p + NTOK;     // SEL_r
    float* thr  = S_p;             // reused after S consumed

    const size_t q_off = 65536;
    const size_t nX = (size_t)NTOK * HH, nW = (size_t)VV * HH;

    unsigned char* Xq  = (unsigned char*)d_ws + q_off;
    unsigned char* Wq  = Xq + nX;
    unsigned char* Xrq = Wq + nW;
    unsigned char* Wrq = Xrq + nX;

    hipLaunchKernelGGL(grpo_init, dim3(8), dim3(1024), 0, stream, S_p);

    hipLaunchKernelGGL(grpo_cvt_all, dim3(4096), dim3(256), 0, stream,
                       X, W, Xr, Wr, Xq, Wq, Xrq, Wrq);

    dim3 grid(NTOK / BM, VV / BN, 2);   // 32 x 125 x 2; m fastest
    hipLaunchKernelGGL(grpo_gemm_f8, grid, dim3(512), 0, stream,
                       Xq, Wq, Xrq, Wrq, ids, S_p, lp_p, S_r, lp_r);

    hipLaunchKernelGGL(grpo_prep,   dim3(4),  dim3(1024), 0, stream, S_p, S_r, lp_p, lp_r);
    hipLaunchKernelGGL(grpo_thresh, dim3(64), dim3(64),   0, stream, lp_r, thr);
    hipLaunchKernelGGL(grpo_final,  dim3(1),  dim3(1024), 0, stream, lp_p, lp_r, thr, am, adv, out);
}